// Round 1
// baseline (34.225 us; speedup 1.0000x reference)
//
#include <hip/hip_runtime.h>
#include <hip/hip_bf16.h>

#define SEP_ID 102
#define BB 64
#define SS 512
#define HH 1024

// ---------------- Kernel A: per-batch segment metadata ----------------
// meta[b*4+0] = first_sep (0 if none), +1 = lead_end, +2 = has_sep, +3 = n_sep
__global__ void seg_meta_kernel(const int* __restrict__ ids, int* __restrict__ meta) {
    int b = blockIdx.x;
    __shared__ int s_first, s_last, s_cnt;
    if (threadIdx.x == 0) { s_first = SS; s_last = -1; s_cnt = 0; }
    __syncthreads();
    int s = threadIdx.x;             // blockDim.x == SS == 512
    bool sep = (ids[b * SS + s] == SEP_ID);
    if (sep) {
        atomicMin(&s_first, s);
        atomicMax(&s_last, s);
        atomicAdd(&s_cnt, 1);
    }
    __syncthreads();
    if (threadIdx.x == 0) {
        int has      = (s_cnt >= 1) ? 1 : 0;
        int first    = has ? s_first : 0;
        int lead_end = (s_cnt >= 2) ? s_last : SS;
        meta[b * 4 + 0] = first;
        meta[b * 4 + 1] = lead_end;
        meta[b * 4 + 2] = has;
        meta[b * 4 + 3] = s_cnt;
    }
}

// ---------------- Kernel B: partial sums over s-chunks ----------------
// grid = (NS, B); block = 256 threads, thread t owns floats [4t, 4t+4) of H.
// part layout: part[((b*NS + sc)*2 + seg)*HH + h], seg 0=title 1=lead
__global__ void pool_partial_kernel(const float* __restrict__ hs,
                                    const int* __restrict__ meta,
                                    float* __restrict__ part,
                                    int NS, int SC) {
    int sc = blockIdx.x;
    int b  = blockIdx.y;
    int first    = meta[b * 4 + 0];
    int lead_end = meta[b * 4 + 1];
    int has      = meta[b * 4 + 2];
    int t = threadIdx.x;

    float4 accT = make_float4(0.f, 0.f, 0.f, 0.f);
    float4 accL = make_float4(0.f, 0.f, 0.f, 0.f);

    int s0 = sc * SC;
    int s1 = s0 + SC; if (s1 > SS) s1 = SS;
    int lo = (s0 > 1) ? s0 : 1;
    int cap = has ? lead_end : 0;          // nothing to read when no sep
    int hi = (s1 < cap) ? s1 : cap;

    const float* rowbase = hs + ((size_t)b * SS) * HH + t * 4;
    for (int s = lo; s < hi; ++s) {
        float4 v = *reinterpret_cast<const float4*>(rowbase + (size_t)s * HH);
        float wT = (s < first) ? 1.f : 0.f;   // lo >= 1 guarantees s >= 1
        float wL = (s > first) ? 1.f : 0.f;   // hi <= lead_end guarantees s < lead_end
        accT.x += v.x * wT; accT.y += v.y * wT; accT.z += v.z * wT; accT.w += v.w * wT;
        accL.x += v.x * wL; accL.y += v.y * wL; accL.z += v.z * wL; accL.w += v.w * wL;
    }

    size_t base = (((size_t)b * NS + sc) * 2) * HH + t * 4;
    *reinterpret_cast<float4*>(part + base)      = accT;
    *reinterpret_cast<float4*>(part + base + HH) = accL;
}

// ---------------- Kernel C: fixed-order reduce + divide ----------------
__global__ void finalize_kernel(const float* __restrict__ part,
                                const int* __restrict__ meta,
                                float* __restrict__ out,
                                int NS) {
    int idx = blockIdx.x * blockDim.x + threadIdx.x;   // over B*H
    int b = idx >> 10;          // H == 1024
    int h = idx & (HH - 1);
    int first    = meta[b * 4 + 0];
    int lead_end = meta[b * 4 + 1];
    int has      = meta[b * 4 + 2];

    float sT = 0.f, sL = 0.f;
    for (int sc = 0; sc < NS; ++sc) {
        size_t base = (((size_t)b * NS + sc) * 2) * HH + h;
        sT += part[base];
        sL += part[base + HH];
    }
    int cT = has ? (first - 1) : 0;            if (cT < 0) cT = 0;
    int cL = has ? (lead_end - first - 1) : 0; if (cL < 0) cL = 0;

    out[(size_t)b * HH + h]                     = (cT > 0) ? sT / (float)cT : 0.f;
    out[(size_t)BB * HH + (size_t)b * HH + h]   = (cL > 0) ? sL / (float)cL : 0.f;
}

extern "C" void kernel_launch(void* const* d_in, const int* in_sizes, int n_in,
                              void* d_out, int out_size, void* d_ws, size_t ws_size,
                              hipStream_t stream) {
    const float* hs = (const float*)d_in[0];
    const int*  ids = (const int*)d_in[1];
    float* out = (float*)d_out;

    int* meta = (int*)d_ws;
    const size_t metaBytes = 1024;   // 64 batches * 4 ints * 4 B = 1 KiB (padded)

    // adaptive NS so partial buffer fits ws
    int NS = 8;
    while (NS > 1 && metaBytes + (size_t)BB * NS * 2 * HH * sizeof(float) > ws_size) NS >>= 1;
    float* part = (float*)((char*)d_ws + metaBytes);

    seg_meta_kernel<<<BB, SS, 0, stream>>>(ids, meta);

    int SC = (SS + NS - 1) / NS;
    dim3 gridB(NS, BB);
    pool_partial_kernel<<<gridB, 256, 0, stream>>>(hs, meta, part, NS, SC);

    finalize_kernel<<<(BB * HH) / 256, 256, 0, stream>>>(part, meta, out, NS);
}